// Round 9
// baseline (5823.658 us; speedup 1.0000x reference)
//
#include <hip/hip_runtime.h>

// Pointer network: encoder LSTM -> enc_proj -> decoder LSTM + attention argmax.
// B=512, S=100, D=2, H=256.
//
// NUMERICS (FROZEN since R7, absmax 7.0 <= 7.2): f64 state trajectory (h/c/
// gates/ep/dp in f64; chain ORDER may vary -- error ~1e-13 << decision gaps)
// + EXACT np-faithful fp32 log_softmax selection (single f32 rounding of
// scores, pairwise-8 sum of exps, lp=fl(fl(s-m)-L), argmax(lp) first-index,
// lp_acc sequential fp32). Selection fp32 ops byte-identical to R7-R19.
//
// R12 block-private. R13 1-butterfly scores + fast f64 tanh. R14 k-split.
// R15 batch-pair blocks. R16 merged k-loop. R17b 4-way k-split 1024-thr
// (4 waves/SIMD; 7.6->6.0 ms). R18 wave-specialized overlap REGRESSED.
// R19 depth-3 rotating ep prefetch (6.0->5.9 steady, bench 5.90->5.30).
// R20: PIPELINE PROLOGUE HOISTED OVER THE K-LOOP. The score phase's cold
//  start (initial A/B/C fills issued at phase entry) still ate a full L3/HBM
//  latency for round 0 every step. slist depends only on masks = known at
//  the PREVIOUS step's tail -> compute slist between bar4/bar5 (same values,
//  earlier); score waves issue the 3 initial ep loads BEFORE the merged
//  k-loop, whose ~2500 cycles blanket the load latency. Zero numerics change.

#define B_WHE  0ull                       // f32 [256 k][256 u][4 g] enc Whh^T
#define B_WHD  (B_WHE + 1048576ull)       // f32 dec
#define B_WET  (B_WHD + 1048576ull)       // f32 [256 k][256 u] We^T
#define B_WDT  (B_WET + 262144ull)        // Wd^T
#define B_WXE  (B_WDT + 262144ull)        // f64 [256 u][16] Wih+bias pack
#define B_WXD  (B_WXE + 32768ull)
#define B_EP   (B_WXD + 32768ull)         // f64 [512 b][100 t][256 u] = 104.9MB

__device__ __forceinline__ double sigmoid_d(double x) {
  return 1.0 / (1.0 + exp(-x));
}

// ---------- R13 branch-free f64 tanh (attention scores only) ----------
__device__ __forceinline__ double exp_pos_d(double a) {  // a in [0, 45]
  const double L2E    = 1.4426950408889634074;
  const double LN2_HI = 6.9314718036912381649e-01;   // ln2 hi (20 low bits 0)
  const double LN2_LO = 1.9082149292705877000e-10;
  const double nf = rint(a * L2E);
  double t = __builtin_fma(-nf, LN2_HI, a);
  t = __builtin_fma(-nf, LN2_LO, t);
  double p = 2.0876756987868099e-09;                 // 1/12!
  p = __builtin_fma(p, t, 2.5052108385441720e-08);   // 1/11!
  p = __builtin_fma(p, t, 2.7557319223985888e-07);
  p = __builtin_fma(p, t, 2.7557319223985893e-06);
  p = __builtin_fma(p, t, 2.4801587301587302e-05);
  p = __builtin_fma(p, t, 1.9841269841269841e-04);
  p = __builtin_fma(p, t, 1.3888888888888889e-03);
  p = __builtin_fma(p, t, 8.3333333333333332e-03);
  p = __builtin_fma(p, t, 4.1666666666666664e-02);
  p = __builtin_fma(p, t, 1.6666666666666666e-01);
  p = __builtin_fma(p, t, 5.0e-01);
  p = __builtin_fma(p, t, 1.0);
  p = __builtin_fma(p, t, 1.0);
  return ldexp(p, (int)nf);
}

__device__ __forceinline__ double fast_div_d(double a, double b) {
  double r = __builtin_amdgcn_rcp(b);                       // ~2^-27
  r = __builtin_fma(__builtin_fma(-b, r, 1.0), r, r);       // NR -> ~2^-53
  r = __builtin_fma(__builtin_fma(-b, r, 1.0), r, r);       // NR -> ~0.5 ulp
  double q = a * r;
  q = __builtin_fma(__builtin_fma(-b, q, a), r, q);         // residual fixup
  return q;
}

__device__ __forceinline__ double tanh_att_d(double x) {
  const double ax = fmin(fabs(x), 22.0);      // tanh(22) == 1.0 in f64
  const double e  = exp_pos_d(2.0 * ax);
  const double r  = 1.0 - fast_div_d(2.0, e + 1.0);
  return copysign(r, x);
}

__device__ __forceinline__ double shfl_xor_d(double v, int m) {
  const long long l = __double_as_longlong(v);
  int lo = (int)(l & 0xffffffffll), hi = (int)(l >> 32);
  lo = __shfl_xor(lo, m, 64);
  hi = __shfl_xor(hi, m, 64);
  return __longlong_as_double(((long long)hi << 32) | (unsigned int)lo);
}

__device__ __forceinline__ double wave64_sum_d(double v) {
  #pragma unroll
  for (int m = 1; m < 64; m <<= 1) v += shfl_xor_d(v, m);
  return v;
}

struct SMem {
  double sredf[104];        // full f64 score sum per s (one butterfly)
  unsigned char slist[104]; // compact list of unmasked s (R20: prev-step tail)
  float  evals[104];        // exp(s-m) staging for the frozen pairwise-8 sum
  float  bc_lp;
  int    bc_sel;
};

extern "C" __global__ void ptrnet_prep(
    const float* __restrict__ eWih, const float* __restrict__ eWhh,
    const float* __restrict__ ebih, const float* __restrict__ ebhh,
    const float* __restrict__ dWih, const float* __restrict__ dWhh,
    const float* __restrict__ dbih, const float* __restrict__ dbhh,
    const float* __restrict__ We,  const float* __restrict__ Wd,
    char* __restrict__ wsb)
{
  const int idx = blockIdx.x * blockDim.x + threadIdx.x;
  const int stride = gridDim.x * blockDim.x;
  float* WHE = (float*)(wsb + B_WHE);
  float* WHD = (float*)(wsb + B_WHD);
  float* WET = (float*)(wsb + B_WET);
  float* WDT = (float*)(wsb + B_WDT);
  double* WXE = (double*)(wsb + B_WXE);
  double* WXD = (double*)(wsb + B_WXD);

  // Whh^T packs: [k][u][gate] (f32 verbatim -- exact)
  for (int i = idx; i < 256*256*4; i += stride) {
    const int g = i & 3, u = (i >> 2) & 255, k = i >> 10;
    WHE[i] = eWhh[(g*256 + u)*256 + k];
    WHD[i] = dWhh[(g*256 + u)*256 + k];
  }
  // We^T / Wd^T: [k][u]
  for (int i = idx; i < 256*256; i += stride) {
    const int u = i & 255, k = i >> 8;
    WET[i] = We[u*256 + k];
    WDT[i] = Wd[u*256 + k];
  }
  // Wih + bias pack (f64): [u][16] = {i0,i1,f0,f1,g0,g1,o0,o1, bi,bf,bg,bo}
  for (int i = idx; i < 256*16; i += stride) {
    const int f = i & 15, u = i >> 4;
    double ve = 0.0, vd = 0.0;
    if (f < 8) {
      const int gg = f >> 1, d = f & 1;
      ve = (double)eWih[(gg*256+u)*2 + d];
      vd = (double)dWih[(gg*256+u)*2 + d];
    } else if (f < 12) {
      const int gg = f - 8;
      ve = (double)ebih[gg*256+u] + (double)ebhh[gg*256+u];
      vd = (double)dbih[gg*256+u] + (double)dbhh[gg*256+u];
    }
    WXE[i] = ve;
    WXD[i] = vd;
  }
}

extern "C" __global__ void __launch_bounds__(1024, 4)
ptrnet_main(char* __restrict__ wsb,
            const float* __restrict__ x,
            const float* __restrict__ be,
            const float* __restrict__ bd,
            const float* __restrict__ Vw,
            const float* __restrict__ Vb,
            const float* __restrict__ start,
            float* __restrict__ out)
{
  __shared__ double hls[2][2][256];     // [parity][batch][u] h state
  __shared__ double dls[2][256];        // [batch][u] dec_proj row
  __shared__ double pred[2][3][256][5]; // [batch][slot][u][stream] partials
  __shared__ SMem sm[2];                // per-batch selection state
  const int b0   = blockIdx.x * 2;      // this block serves batches b0, b1
  const int b1   = b0 + 1;
  const int tid  = threadIdx.x;
  const int u    = tid & 255;           // hidden unit
  const int q    = tid >> 8;            // quarter 0..3; q<2 owns batch q
  const int k0   = q << 6;              // own k range [k0, k0+64)
  const int lane = tid & 63;
  const int w = __builtin_amdgcn_readfirstlane(tid >> 6);   // 0..15

  const float* WHE = (const float*)(wsb + B_WHE);
  const float* WHD = (const float*)(wsb + B_WHD);
  const float* WET = (const float*)(wsb + B_WET);
  const float* WDT = (const float*)(wsb + B_WDT);
  const double* wxE = (const double*)(wsb + B_WXE) + u*16;
  const double* wxD = (const double*)(wsb + B_WXD) + u*16;
  double* ep0 = (double*)(wsb + B_EP) + (size_t)b0*25600;
  double* ep1 = (double*)(wsb + B_EP) + (size_t)b1*25600;

  const double be_u = (double)be[u];
  const double bd_u = (double)bd[u];
  const double vb0  = (double)Vb[0];
  // per-lane Vw quad (u' = 4*lane + j), loop-invariant over all steps
  const double vq0 = (double)Vw[lane*4 + 0];
  const double vq1 = (double)Vw[lane*4 + 1];
  const double vq2 = (double)Vw[lane*4 + 2];
  const double vq3 = (double)Vw[lane*4 + 3];

  double c_state = 0.0;                 // owned batch's c (valid on q<2)
  int par = 0;
  if (tid < 256) { hls[0][0][tid] = 0.0; hls[0][1][tid] = 0.0; }
  __syncthreads();

  // ============================ encoder ============================
  for (int t = 0; t < 100; ++t) {
    const double x00 = (double)x[(b0*100 + t)*2 + 0];
    const double x01 = (double)x[(b0*100 + t)*2 + 1];
    const double x10 = (double)x[(b1*100 + t)*2 + 0];
    const double x11 = (double)x[(b1*100 + t)*2 + 1];
    double p0 = 0.0, p1 = 0.0, p2 = 0.0, p3 = 0.0, p4 = 0.0;  // b0 partials
    double q0 = 0.0, q1 = 0.0, q2 = 0.0, q3 = 0.0, q4 = 0.0;  // b1 partials
    const double* h0 = hls[par][0];
    const double* h1 = hls[par][1];
    #pragma unroll 8
    for (int k = k0; k < k0 + 64; ++k) {
      const double hk0 = h0[k];                      // LDS broadcast
      const double hk1 = h1[k];
      const float4 wf = *(const float4*)(WHE + k*1024 + u*4);
      const float  we = WET[k*256 + u];
      const double wx = (double)wf.x, wy = (double)wf.y;
      const double wz = (double)wf.z, ww = (double)wf.w;
      const double wv = (double)we;                  // one load+cvt, two FMAs
      p0 = fma(wx, hk0, p0);  q0 = fma(wx, hk1, q0);
      p1 = fma(wy, hk0, p1);  q1 = fma(wy, hk1, q1);
      p2 = fma(wz, hk0, p2);  q2 = fma(wz, hk1, q2);
      p3 = fma(ww, hk0, p3);  q3 = fma(ww, hk1, q3);
      p4 = fma(wv, hk0, p4);  q4 = fma(wv, hk1, q4);
    }
    if (q == 0) {
      pred[1][0][u][0] = q0; pred[1][0][u][1] = q1; pred[1][0][u][2] = q2;
      pred[1][0][u][3] = q3; pred[1][0][u][4] = q4;
    } else if (q == 1) {
      pred[0][0][u][0] = p0; pred[0][0][u][1] = p1; pred[0][0][u][2] = p2;
      pred[0][0][u][3] = p3; pred[0][0][u][4] = p4;
    } else {
      const int sl = q - 1;   // slots 1,2
      pred[0][sl][u][0] = p0; pred[0][sl][u][1] = p1; pred[0][sl][u][2] = p2;
      pred[0][sl][u][3] = p3; pred[0][sl][u][4] = p4;
      pred[1][sl][u][0] = q0; pred[1][sl][u][1] = q1; pred[1][sl][u][2] = q2;
      pred[1][sl][u][3] = q3; pred[1][sl][u][4] = q4;
    }
    __syncthreads();
    if (q < 2) {
      const double o0 = q ? q0 : p0, o1 = q ? q1 : p1, o2 = q ? q2 : p2;
      const double o3 = q ? q3 : p3, o4 = q ? q4 : p4;
      const double a0 = o0 + pred[q][0][u][0] + pred[q][1][u][0] + pred[q][2][u][0];
      const double a1 = o1 + pred[q][0][u][1] + pred[q][1][u][1] + pred[q][2][u][1];
      const double a2 = o2 + pred[q][0][u][2] + pred[q][1][u][2] + pred[q][2][u][2];
      const double a3 = o3 + pred[q][0][u][3] + pred[q][1][u][3] + pred[q][2][u][3];
      const double ae = o4 + pred[q][0][u][4] + pred[q][1][u][4] + pred[q][2][u][4];
      const double xg0 = q ? x10 : x00;
      const double xg1 = q ? x11 : x01;
      const double gi = a0 + fma(wxE[0], xg0, fma(wxE[1], xg1, wxE[8]));
      const double gf = a1 + fma(wxE[2], xg0, fma(wxE[3], xg1, wxE[9]));
      const double gg = a2 + fma(wxE[4], xg0, fma(wxE[5], xg1, wxE[10]));
      const double go = a3 + fma(wxE[6], xg0, fma(wxE[7], xg1, wxE[11]));
      const double cn = sigmoid_d(gf)*c_state + sigmoid_d(gi)*tanh(gg);
      const double hn = sigmoid_d(go)*tanh(cn);
      c_state = cn;
      if (t > 0) (q ? ep1 : ep0)[(t-1)*256 + u] = ae + be_u;
      hls[par ^ 1][q][u] = hn;
    }
    __syncthreads();
    par ^= 1;
  }
  // ep[99] from h^(100)
  {
    double ae0 = 0.0, ae1 = 0.0;
    const double* h0 = hls[par][0];
    const double* h1 = hls[par][1];
    #pragma unroll 8
    for (int k = k0; k < k0 + 64; ++k) {
      const double wv = (double)WET[k*256 + u];
      ae0 = fma(wv, h0[k], ae0);
      ae1 = fma(wv, h1[k], ae1);
    }
    if (q == 0) {
      pred[1][0][u][0] = ae1;
    } else if (q == 1) {
      pred[0][0][u][0] = ae0;
    } else {
      const int sl = q - 1;
      pred[0][sl][u][0] = ae0;
      pred[1][sl][u][0] = ae1;
    }
    __syncthreads();
    if (q < 2) {
      const double own = q ? ae1 : ae0;
      const double ae = own + pred[q][0][u][0] + pred[q][1][u][0] + pred[q][2][u][0];
      (q ? ep1 : ep0)[99*256 + u] = ae + be_u;
    }
    __syncthreads();   // fence pred reads vs decoder-prologue deposits (R17b)
  }

  // ===================== decoder =====================
  // both batches' masks tracked block-uniformly in every thread
  unsigned long long ma0 = 0ull, ma1 = 0ull;   // b0 mask
  unsigned long long mb0 = 0ull, mb1 = 0ull;   // b1 mask
  float lp_acc = 0.0f;

  // ---- prologue: LSTM(0) with din = start (h,c carry over from encoder) ----
  {
    const double sx0 = (double)start[0];
    const double sx1 = (double)start[1];
    double p0 = 0.0, p1 = 0.0, p2 = 0.0, p3 = 0.0;
    double q0 = 0.0, q1 = 0.0, q2 = 0.0, q3 = 0.0;
    const double* h0 = hls[par][0];
    const double* h1 = hls[par][1];
    #pragma unroll 8
    for (int k = k0; k < k0 + 64; ++k) {
      const double hk0 = h0[k];
      const double hk1 = h1[k];
      const float4 wf = *(const float4*)(WHD + k*1024 + u*4);
      const double wx = (double)wf.x, wy = (double)wf.y;
      const double wz = (double)wf.z, ww = (double)wf.w;
      p0 = fma(wx, hk0, p0);  q0 = fma(wx, hk1, q0);
      p1 = fma(wy, hk0, p1);  q1 = fma(wy, hk1, q1);
      p2 = fma(wz, hk0, p2);  q2 = fma(wz, hk1, q2);
      p3 = fma(ww, hk0, p3);  q3 = fma(ww, hk1, q3);
    }
    if (q == 0) {
      pred[1][0][u][0] = q0; pred[1][0][u][1] = q1;
      pred[1][0][u][2] = q2; pred[1][0][u][3] = q3;
    } else if (q == 1) {
      pred[0][0][u][0] = p0; pred[0][0][u][1] = p1;
      pred[0][0][u][2] = p2; pred[0][0][u][3] = p3;
    } else {
      const int sl = q - 1;
      pred[0][sl][u][0] = p0; pred[0][sl][u][1] = p1;
      pred[0][sl][u][2] = p2; pred[0][sl][u][3] = p3;
      pred[1][sl][u][0] = q0; pred[1][sl][u][1] = q1;
      pred[1][sl][u][2] = q2; pred[1][sl][u][3] = q3;
    }
    // R20: initial all-unmasked slist for step 0 (masks are zero)
    if (tid < 100) {
      sm[0].slist[tid] = (unsigned char)tid;
      sm[1].slist[tid] = (unsigned char)tid;
    }
    __syncthreads();
    if (q < 2) {
      const double o0 = q ? q0 : p0, o1 = q ? q1 : p1;
      const double o2 = q ? q2 : p2, o3 = q ? q3 : p3;
      const double a0 = o0 + pred[q][0][u][0] + pred[q][1][u][0] + pred[q][2][u][0];
      const double a1 = o1 + pred[q][0][u][1] + pred[q][1][u][1] + pred[q][2][u][1];
      const double a2 = o2 + pred[q][0][u][2] + pred[q][1][u][2] + pred[q][2][u][2];
      const double a3 = o3 + pred[q][0][u][3] + pred[q][1][u][3] + pred[q][2][u][3];
      const double gi = a0 + fma(wxD[0], sx0, fma(wxD[1], sx1, wxD[8]));
      const double gf = a1 + fma(wxD[2], sx0, fma(wxD[3], sx1, wxD[9]));
      const double gg = a2 + fma(wxD[4], sx0, fma(wxD[5], sx1, wxD[10]));
      const double go = a3 + fma(wxD[6], sx0, fma(wxD[7], sx1, wxD[11]));
      const double cn = sigmoid_d(gf)*c_state + sigmoid_d(gi)*tanh(gg);
      const double hn = sigmoid_d(go)*tanh(cn);
      c_state = cn;
      hls[par ^ 1][q][u] = hn;
    }
    __syncthreads();
    par ^= 1;
  }

  for (int t = 0; t < 100; ++t) {
    const int scnt = 100 - t;
    const int bw = w >> 3;                // score batch for this wave
    const int wi = w & 7;
    const double* epb = bw ? ep1 : ep0;
    // ---- R20: issue depth-3 initial ep loads BEFORE the k-loop ----
    // slist was written at the previous step's tail (bar5-fenced); the
    // merged k-loop's ~2500 cycles blanket these loads' latency.
    int sA = 0, sB = 0, sC = 0;
    double2 A01 = {0.0, 0.0}, A23 = {0.0, 0.0};
    double2 B01 = {0.0, 0.0}, B23 = {0.0, 0.0};
    double2 C01 = {0.0, 0.0}, C23 = {0.0, 0.0};
    if (wi < scnt) {
      sA = (int)sm[bw].slist[wi];
      const double* er = epb + sA*256 + lane*4;
      A01 = *(const double2*)(er);  A23 = *(const double2*)(er + 2);
    }
    if (wi + 8 < scnt) {
      sB = (int)sm[bw].slist[wi + 8];
      const double* er = epb + sB*256 + lane*4;
      B01 = *(const double2*)(er);  B23 = *(const double2*)(er + 2);
    }
    if (wi + 16 < scnt) {
      sC = (int)sm[bw].slist[wi + 16];
      const double* er = epb + sC*256 + lane*4;
      C01 = *(const double2*)(er);  C23 = *(const double2*)(er + 2);
    }
    // ---- merged k-loop over h(t): dec_proj(t) + LSTM partials for t+1 ----
    double go0, go1, go2, go3, dpo;   // own-batch survivors (regs thru select)
    {
      double p0 = 0.0, p1 = 0.0, p2 = 0.0, p3 = 0.0, pd = 0.0;  // b0
      double q0 = 0.0, q1 = 0.0, q2 = 0.0, q3 = 0.0, qd = 0.0;  // b1
      const double* h0 = hls[par][0];
      const double* h1 = hls[par][1];
      #pragma unroll 8
      for (int k = k0; k < k0 + 64; ++k) {
        const double hk0 = h0[k];
        const double hk1 = h1[k];
        const float4 wf = *(const float4*)(WHD + k*1024 + u*4);
        const float  wd = WDT[k*256 + u];
        const double wx = (double)wf.x, wy = (double)wf.y;
        const double wz = (double)wf.z, ww = (double)wf.w;
        const double wv = (double)wd;
        p0 = fma(wx, hk0, p0);  q0 = fma(wx, hk1, q0);
        p1 = fma(wy, hk0, p1);  q1 = fma(wy, hk1, q1);
        p2 = fma(wz, hk0, p2);  q2 = fma(wz, hk1, q2);
        p3 = fma(ww, hk0, p3);  q3 = fma(ww, hk1, q3);
        pd = fma(wv, hk0, pd);  qd = fma(wv, hk1, qd);
      }
      if (q == 0) {
        pred[1][0][u][0] = q0; pred[1][0][u][1] = q1; pred[1][0][u][2] = q2;
        pred[1][0][u][3] = q3; pred[1][0][u][4] = qd;
      } else if (q == 1) {
        pred[0][0][u][0] = p0; pred[0][0][u][1] = p1; pred[0][0][u][2] = p2;
        pred[0][0][u][3] = p3; pred[0][0][u][4] = pd;
      } else {
        const int sl = q - 1;
        pred[0][sl][u][0] = p0; pred[0][sl][u][1] = p1; pred[0][sl][u][2] = p2;
        pred[0][sl][u][3] = p3; pred[0][sl][u][4] = pd;
        pred[1][sl][u][0] = q0; pred[1][sl][u][1] = q1; pred[1][sl][u][2] = q2;
        pred[1][sl][u][3] = q3; pred[1][sl][u][4] = qd;
      }
      go0 = q ? q0 : p0;  go1 = q ? q1 : p1;
      go2 = q ? q2 : p2;  go3 = q ? q3 : p3;
      dpo = q ? qd : pd;
    }
    __syncthreads();                                   // bar1
    // dec_proj combine (owning quarters)
    if (q < 2) {
      dls[q][u] = dpo + pred[q][0][u][4] + pred[q][1][u][4] + pred[q][2][u][4]
                  + bd_u;
    }
    __syncthreads();                                   // bar2
    // ---- f64-exact scores: waves 0-7 b0, waves 8-15 b1 ----
    // depth-3 rotating prefetch (R19); initial fills already hot (R20)
    {
      const double dpq0 = dls[bw][lane*4 + 0];
      const double dpq1 = dls[bw][lane*4 + 1];
      const double dpq2 = dls[bw][lane*4 + 2];
      const double dpq3 = dls[bw][lane*4 + 3];
      for (int i = wi; i < scnt; i += 8) {
        // issue the load 3 rounds ahead FIRST, then compute round i
        int sN = 0;
        double2 N01 = {0.0, 0.0}, N23 = {0.0, 0.0};
        const int inx = i + 24;
        if (inx < scnt) {
          sN = (int)sm[bw].slist[inx];
          const double* er = epb + sN*256 + lane*4;
          N01 = *(const double2*)(er);  N23 = *(const double2*)(er + 2);
        }
        double p =        tanh_att_d(A01.x + dpq0) * vq0;
        p = __builtin_fma(tanh_att_d(A01.y + dpq1), vq1, p);
        p = __builtin_fma(tanh_att_d(A23.x + dpq2), vq2, p);
        p = __builtin_fma(tanh_att_d(A23.y + dpq3), vq3, p);
        p = wave64_sum_d(p);
        if (lane == 0) sm[bw].sredf[sA] = p;
        sA = sB; A01 = B01; A23 = B23;
        sB = sC; B01 = C01; B23 = C23;
        sC = sN; C01 = N01; C23 = N23;
      }
    }
    __syncthreads();                                   // bar3
    // ---- np-faithful fp32 selection, condensed into wave 0 / wave 8 ----
    if ((w & 7) == 0) {
      const int bb = w >> 3;
      const unsigned long long km0 = bb ? mb0 : ma0;
      const unsigned long long km1 = bb ? mb1 : ma1;
      const bool mk0 = ((km0 >> lane) & 1ull) != 0ull;
      const bool mk1 = (lane < 36) ? (((km1 >> lane) & 1ull) != 0ull) : true;
      const int  s1i = 64 + (lane < 36 ? lane : 0);
      // single rounding of the exact score to fp32 (reference dtype)
      const float sc0 = mk0 ? -__builtin_inff()
                            : (float)(sm[bb].sredf[lane] + vb0);
      const float sc1 = mk1 ? -__builtin_inff()
                            : (float)(sm[bb].sredf[s1i] + vb0);
      // m = max(scores), fp32 -- identical fmax tree as frozen block
      float mv = fmaxf(sc0, sc1);
      #pragma unroll
      for (int mm = 1; mm < 64; mm <<= 1)
        mv = fmaxf(mv, __shfl_xor(mv, mm, 64));
      // evals = expf(s - m), staged to LDS in the frozen index layout
      sm[bb].evals[lane] = expf(__fsub_rn(sc0, mv));
      if (lane < 36) sm[bb].evals[64 + lane] = expf(__fsub_rn(sc1, mv));
      // same-wave LDS visibility: fence compiler + lgkm before read-back
      asm volatile("s_waitcnt lgkmcnt(0)" ::: "memory");
      __builtin_amdgcn_sched_barrier(0);
      // numpy pairwise_sum for n=100 (frozen): 8 accumulators over 0..95,
      // combine ((r0+r1)+(r2+r3))+((r4+r5)+(r6+r7)), sequential tail 96..99
      float rr[8];
      #pragma unroll
      for (int j = 0; j < 8; ++j) rr[j] = sm[bb].evals[j];
      for (int i = 8; i < 96; i += 8) {
        #pragma unroll
        for (int j = 0; j < 8; ++j) rr[j] = __fadd_rn(rr[j], sm[bb].evals[i + j]);
      }
      float res = __fadd_rn(
          __fadd_rn(__fadd_rn(rr[0], rr[1]), __fadd_rn(rr[2], rr[3])),
          __fadd_rn(__fadd_rn(rr[4], rr[5]), __fadd_rn(rr[6], rr[7])));
      res = __fadd_rn(res, sm[bb].evals[96]);
      res = __fadd_rn(res, sm[bb].evals[97]);
      res = __fadd_rn(res, sm[bb].evals[98]);
      res = __fadd_rn(res, sm[bb].evals[99]);
      const float L = logf(res);
      // lp = fl(fl(s - m) - L); argmax(lp), first index on ties (frozen)
      const float lp0 = __fsub_rn(__fsub_rn(sc0, mv), L);
      const float lp1 = (lane < 36)
          ? __fsub_rn(__fsub_rn(sc1, mv), L)
          : -__builtin_inff();
      float bv; int bi;
      if (lp0 >= lp1) { bv = lp0; bi = lane; } else { bv = lp1; bi = 64 + lane; }
      #pragma unroll
      for (int mm = 1; mm < 64; mm <<= 1) {
        const float ov = __shfl_xor(bv, mm, 64);
        const int   oi = __shfl_xor(bi, mm, 64);
        if (ov > bv || (ov == bv && oi < bi)) { bv = ov; bi = oi; }
      }
      if (lane == 0) { sm[bb].bc_sel = bi; sm[bb].bc_lp = bv; }
    }
    __syncthreads();                                   // bar4
    const int sel0 = __builtin_amdgcn_readfirstlane(sm[0].bc_sel);
    const int sel1 = __builtin_amdgcn_readfirstlane(sm[1].bc_sel);
    lp_acc = __fadd_rn(lp_acc, sm[q & 1].bc_lp);  // np axis-0 sum: seq fp32
    if (sel0 < 64) ma0 |= (1ull << sel0); else ma1 |= (1ull << (sel0 - 64));
    if (sel1 < 64) mb0 |= (1ull << sel1); else mb1 |= (1ull << (sel1 - 64));
    if (tid == 0)   out[b0*100 + t] = (float)sel0;
    if (tid == 256) out[b1*100 + t] = (float)sel1;
    // ---- R20: slist for the NEXT step (masks just updated) ----
    if (t < 99 && q < 2 && u < 100) {
      const unsigned long long km0 = q ? mb0 : ma0;
      const unsigned long long km1 = q ? mb1 : ma1;
      const unsigned long long um0 = ~km0;
      const unsigned long long um1 = (~km1) & 0xFFFFFFFFFull;  // 36 bits
      bool unm; int pre;
      if (u < 64) {
        unm = ((um0 >> u) & 1ull) != 0ull;
        pre = __popcll(um0 & ((1ull << u) - 1ull));
      } else {
        const int r = u - 64;
        unm = ((um1 >> r) & 1ull) != 0ull;
        pre = __popcll(um0) + __popcll(um1 & ((1ull << r) - 1ull));
      }
      if (unm) sm[q].slist[pre] = (unsigned char)u;
    }
    // ---- finalize LSTM(t+1): gates = partials + Wih*din + bias ----
    if (t < 99) {
      if (q < 2) {
        const int sel = q ? sel1 : sel0;
        const int bb  = q ? b1 : b0;
        const double xd0 = (double)x[(bb*100 + sel)*2 + 0];  // uniform load
        const double xd1 = (double)x[(bb*100 + sel)*2 + 1];
        const double a0 = go0 + pred[q][0][u][0] + pred[q][1][u][0] + pred[q][2][u][0];
        const double a1 = go1 + pred[q][0][u][1] + pred[q][1][u][1] + pred[q][2][u][1];
        const double a2 = go2 + pred[q][0][u][2] + pred[q][1][u][2] + pred[q][2][u][2];
        const double a3 = go3 + pred[q][0][u][3] + pred[q][1][u][3] + pred[q][2][u][3];
        const double gi = a0 + fma(wxD[0], xd0, fma(wxD[1], xd1, wxD[8]));
        const double gf = a1 + fma(wxD[2], xd0, fma(wxD[3], xd1, wxD[9]));
        const double gg = a2 + fma(wxD[4], xd0, fma(wxD[5], xd1, wxD[10]));
        const double go = a3 + fma(wxD[6], xd0, fma(wxD[7], xd1, wxD[11]));
        const double cn = sigmoid_d(gf)*c_state + sigmoid_d(gi)*tanh(gg);
        const double hn = sigmoid_d(go)*tanh(cn);
        c_state = cn;
        hls[par ^ 1][q][u] = hn;
      }
      par ^= 1;
    }
    __syncthreads();                                   // bar5
  }

  // ---------------- outputs ----------------
  if (tid == 0)   out[51200 + b0] = lp_acc;
  if (tid == 256) out[51200 + b1] = lp_acc;
  if (q < 2) out[51712 + (q ? b1 : b0)*256 + u] = (float)hls[par][q][u];
}

extern "C" void kernel_launch(void* const* d_in, const int* in_sizes, int n_in,
                              void* d_out, int out_size, void* d_ws, size_t ws_size,
                              hipStream_t stream) {
  const float* x     = (const float*)d_in[0];
  const float* eWih  = (const float*)d_in[1];
  const float* eWhh  = (const float*)d_in[2];
  const float* ebih  = (const float*)d_in[3];
  const float* ebhh  = (const float*)d_in[4];
  const float* dWih  = (const float*)d_in[5];
  const float* dWhh  = (const float*)d_in[6];
  const float* dbih  = (const float*)d_in[7];
  const float* dbhh  = (const float*)d_in[8];
  const float* We    = (const float*)d_in[9];
  const float* be    = (const float*)d_in[10];
  const float* Wd    = (const float*)d_in[11];
  const float* bd    = (const float*)d_in[12];
  const float* vw    = (const float*)d_in[13];
  const float* vb    = (const float*)d_in[14];
  const float* start = (const float*)d_in[15];
  char* ws    = (char*)d_ws;
  float* outp = (float*)d_out;

  ptrnet_prep<<<dim3(512), dim3(256), 0, stream>>>(
      eWih, eWhh, ebih, ebhh, dWih, dWhh, dbih, dbhh, We, Wd, ws);

  ptrnet_main<<<dim3(256), dim3(1024), 0, stream>>>(ws, x, be, bd, vw, vb,
                                                    start, outp);
}

// Round 10
// 5289.669 us; speedup vs baseline: 1.1009x; 1.1009x over previous
//
#include <hip/hip_runtime.h>

// Pointer network: encoder LSTM -> enc_proj -> decoder LSTM + attention argmax.
// B=512, S=100, D=2, H=256.
//
// NUMERICS (FROZEN since R7, absmax 7.0 <= 7.2): f64 state trajectory (h/c/
// gates/ep/dp in f64; chain ORDER may vary -- error ~1e-13 << decision gaps)
// + EXACT np-faithful fp32 log_softmax selection (single f32 rounding of
// scores, pairwise-8 sum of exps, lp=fl(fl(s-m)-L), argmax(lp) first-index,
// lp_acc sequential fp32). Selection fp32 ops byte-identical to R7-R19.
//
// R12 block-private. R13 1-butterfly scores + fast f64 tanh. R14 k-split.
// R15 batch-pair blocks. R16 merged k-loop. R17b 4-way k-split 1024-thr.
// R18 wave-specialized overlap REGRESSED (reverted). R19 depth-3 rotating
// ep prefetch (bench 5.90->5.30). R20 prologue-hoist REGRESSED: early ep
// loads evicted shared weight lines from L2 (FETCH 3.0->4.2GB) -- reverted.
// R21: R19 + BARRIER MERGE (5->4/step), bit-identical. All 4 quarters
//  deposit dp partials to pdp[2][4][256] during the k-loop; score waves
//  combine (((q0+q1)+q2)+q3)+bd themselves. b0 order == R19 exactly; b1
//  differs only by the commutative swap q1+q0 -> q0+q1 (IEEE bit-identical).
//  dls array + one full-block barrier eliminated; slist moved before bar1
//  (same masks, same values).

#define B_WHE  0ull                       // f32 [256 k][256 u][4 g] enc Whh^T
#define B_WHD  (B_WHE + 1048576ull)       // f32 dec
#define B_WET  (B_WHD + 1048576ull)       // f32 [256 k][256 u] We^T
#define B_WDT  (B_WET + 262144ull)        // Wd^T
#define B_WXE  (B_WDT + 262144ull)        // f64 [256 u][16] Wih+bias pack
#define B_WXD  (B_WXE + 32768ull)
#define B_EP   (B_WXD + 32768ull)         // f64 [512 b][100 t][256 u] = 104.9MB

__device__ __forceinline__ double sigmoid_d(double x) {
  return 1.0 / (1.0 + exp(-x));
}

// ---------- R13 branch-free f64 tanh (attention scores only) ----------
__device__ __forceinline__ double exp_pos_d(double a) {  // a in [0, 45]
  const double L2E    = 1.4426950408889634074;
  const double LN2_HI = 6.9314718036912381649e-01;   // ln2 hi (20 low bits 0)
  const double LN2_LO = 1.9082149292705877000e-10;
  const double nf = rint(a * L2E);
  double t = __builtin_fma(-nf, LN2_HI, a);
  t = __builtin_fma(-nf, LN2_LO, t);
  double p = 2.0876756987868099e-09;                 // 1/12!
  p = __builtin_fma(p, t, 2.5052108385441720e-08);   // 1/11!
  p = __builtin_fma(p, t, 2.7557319223985888e-07);
  p = __builtin_fma(p, t, 2.7557319223985893e-06);
  p = __builtin_fma(p, t, 2.4801587301587302e-05);
  p = __builtin_fma(p, t, 1.9841269841269841e-04);
  p = __builtin_fma(p, t, 1.3888888888888889e-03);
  p = __builtin_fma(p, t, 8.3333333333333332e-03);
  p = __builtin_fma(p, t, 4.1666666666666664e-02);
  p = __builtin_fma(p, t, 1.6666666666666666e-01);
  p = __builtin_fma(p, t, 5.0e-01);
  p = __builtin_fma(p, t, 1.0);
  p = __builtin_fma(p, t, 1.0);
  return ldexp(p, (int)nf);
}

__device__ __forceinline__ double fast_div_d(double a, double b) {
  double r = __builtin_amdgcn_rcp(b);                       // ~2^-27
  r = __builtin_fma(__builtin_fma(-b, r, 1.0), r, r);       // NR -> ~2^-53
  r = __builtin_fma(__builtin_fma(-b, r, 1.0), r, r);       // NR -> ~0.5 ulp
  double q = a * r;
  q = __builtin_fma(__builtin_fma(-b, q, a), r, q);         // residual fixup
  return q;
}

__device__ __forceinline__ double tanh_att_d(double x) {
  const double ax = fmin(fabs(x), 22.0);      // tanh(22) == 1.0 in f64
  const double e  = exp_pos_d(2.0 * ax);
  const double r  = 1.0 - fast_div_d(2.0, e + 1.0);
  return copysign(r, x);
}

__device__ __forceinline__ double shfl_xor_d(double v, int m) {
  const long long l = __double_as_longlong(v);
  int lo = (int)(l & 0xffffffffll), hi = (int)(l >> 32);
  lo = __shfl_xor(lo, m, 64);
  hi = __shfl_xor(hi, m, 64);
  return __longlong_as_double(((long long)hi << 32) | (unsigned int)lo);
}

__device__ __forceinline__ double wave64_sum_d(double v) {
  #pragma unroll
  for (int m = 1; m < 64; m <<= 1) v += shfl_xor_d(v, m);
  return v;
}

struct SMem {
  double sredf[104];        // full f64 score sum per s (one butterfly)
  unsigned char slist[104]; // compact list of unmasked s
  float  evals[104];        // exp(s-m) staging for the frozen pairwise-8 sum
  float  bc_lp;
  int    bc_sel;
};

extern "C" __global__ void ptrnet_prep(
    const float* __restrict__ eWih, const float* __restrict__ eWhh,
    const float* __restrict__ ebih, const float* __restrict__ ebhh,
    const float* __restrict__ dWih, const float* __restrict__ dWhh,
    const float* __restrict__ dbih, const float* __restrict__ dbhh,
    const float* __restrict__ We,  const float* __restrict__ Wd,
    char* __restrict__ wsb)
{
  const int idx = blockIdx.x * blockDim.x + threadIdx.x;
  const int stride = gridDim.x * blockDim.x;
  float* WHE = (float*)(wsb + B_WHE);
  float* WHD = (float*)(wsb + B_WHD);
  float* WET = (float*)(wsb + B_WET);
  float* WDT = (float*)(wsb + B_WDT);
  double* WXE = (double*)(wsb + B_WXE);
  double* WXD = (double*)(wsb + B_WXD);

  // Whh^T packs: [k][u][gate] (f32 verbatim -- exact)
  for (int i = idx; i < 256*256*4; i += stride) {
    const int g = i & 3, u = (i >> 2) & 255, k = i >> 10;
    WHE[i] = eWhh[(g*256 + u)*256 + k];
    WHD[i] = dWhh[(g*256 + u)*256 + k];
  }
  // We^T / Wd^T: [k][u]
  for (int i = idx; i < 256*256; i += stride) {
    const int u = i & 255, k = i >> 8;
    WET[i] = We[u*256 + k];
    WDT[i] = Wd[u*256 + k];
  }
  // Wih + bias pack (f64): [u][16] = {i0,i1,f0,f1,g0,g1,o0,o1, bi,bf,bg,bo}
  for (int i = idx; i < 256*16; i += stride) {
    const int f = i & 15, u = i >> 4;
    double ve = 0.0, vd = 0.0;
    if (f < 8) {
      const int gg = f >> 1, d = f & 1;
      ve = (double)eWih[(gg*256+u)*2 + d];
      vd = (double)dWih[(gg*256+u)*2 + d];
    } else if (f < 12) {
      const int gg = f - 8;
      ve = (double)ebih[gg*256+u] + (double)ebhh[gg*256+u];
      vd = (double)dbih[gg*256+u] + (double)dbhh[gg*256+u];
    }
    WXE[i] = ve;
    WXD[i] = vd;
  }
}

extern "C" __global__ void __launch_bounds__(1024, 4)
ptrnet_main(char* __restrict__ wsb,
            const float* __restrict__ x,
            const float* __restrict__ be,
            const float* __restrict__ bd,
            const float* __restrict__ Vw,
            const float* __restrict__ Vb,
            const float* __restrict__ start,
            float* __restrict__ out)
{
  __shared__ double hls[2][2][256];     // [parity][batch][u] h state
  __shared__ double pdp[2][4][256];     // R21: [batch][quarter][u] dp partials
  __shared__ double pred[2][3][256][5]; // [batch][slot][u][stream] partials
  __shared__ SMem sm[2];                // per-batch selection state
  const int b0   = blockIdx.x * 2;      // this block serves batches b0, b1
  const int b1   = b0 + 1;
  const int tid  = threadIdx.x;
  const int u    = tid & 255;           // hidden unit
  const int q    = tid >> 8;            // quarter 0..3; q<2 owns batch q
  const int k0   = q << 6;              // own k range [k0, k0+64)
  const int lane = tid & 63;
  const int w = __builtin_amdgcn_readfirstlane(tid >> 6);   // 0..15

  const float* WHE = (const float*)(wsb + B_WHE);
  const float* WHD = (const float*)(wsb + B_WHD);
  const float* WET = (const float*)(wsb + B_WET);
  const float* WDT = (const float*)(wsb + B_WDT);
  const double* wxE = (const double*)(wsb + B_WXE) + u*16;
  const double* wxD = (const double*)(wsb + B_WXD) + u*16;
  double* ep0 = (double*)(wsb + B_EP) + (size_t)b0*25600;
  double* ep1 = (double*)(wsb + B_EP) + (size_t)b1*25600;

  const double be_u = (double)be[u];
  const double vb0  = (double)Vb[0];
  // per-lane Vw / bd quads (u' = 4*lane + j), loop-invariant over all steps
  const double vq0 = (double)Vw[lane*4 + 0];
  const double vq1 = (double)Vw[lane*4 + 1];
  const double vq2 = (double)Vw[lane*4 + 2];
  const double vq3 = (double)Vw[lane*4 + 3];
  const double bdq0 = (double)bd[lane*4 + 0];
  const double bdq1 = (double)bd[lane*4 + 1];
  const double bdq2 = (double)bd[lane*4 + 2];
  const double bdq3 = (double)bd[lane*4 + 3];

  double c_state = 0.0;                 // owned batch's c (valid on q<2)
  int par = 0;
  if (tid < 256) { hls[0][0][tid] = 0.0; hls[0][1][tid] = 0.0; }
  __syncthreads();

  // ============================ encoder ============================
  for (int t = 0; t < 100; ++t) {
    const double x00 = (double)x[(b0*100 + t)*2 + 0];
    const double x01 = (double)x[(b0*100 + t)*2 + 1];
    const double x10 = (double)x[(b1*100 + t)*2 + 0];
    const double x11 = (double)x[(b1*100 + t)*2 + 1];
    double p0 = 0.0, p1 = 0.0, p2 = 0.0, p3 = 0.0, p4 = 0.0;  // b0 partials
    double q0 = 0.0, q1 = 0.0, q2 = 0.0, q3 = 0.0, q4 = 0.0;  // b1 partials
    const double* h0 = hls[par][0];
    const double* h1 = hls[par][1];
    #pragma unroll 8
    for (int k = k0; k < k0 + 64; ++k) {
      const double hk0 = h0[k];                      // LDS broadcast
      const double hk1 = h1[k];
      const float4 wf = *(const float4*)(WHE + k*1024 + u*4);
      const float  we = WET[k*256 + u];
      const double wx = (double)wf.x, wy = (double)wf.y;
      const double wz = (double)wf.z, ww = (double)wf.w;
      const double wv = (double)we;                  // one load+cvt, two FMAs
      p0 = fma(wx, hk0, p0);  q0 = fma(wx, hk1, q0);
      p1 = fma(wy, hk0, p1);  q1 = fma(wy, hk1, q1);
      p2 = fma(wz, hk0, p2);  q2 = fma(wz, hk1, q2);
      p3 = fma(ww, hk0, p3);  q3 = fma(ww, hk1, q3);
      p4 = fma(wv, hk0, p4);  q4 = fma(wv, hk1, q4);
    }
    if (q == 0) {
      pred[1][0][u][0] = q0; pred[1][0][u][1] = q1; pred[1][0][u][2] = q2;
      pred[1][0][u][3] = q3; pred[1][0][u][4] = q4;
    } else if (q == 1) {
      pred[0][0][u][0] = p0; pred[0][0][u][1] = p1; pred[0][0][u][2] = p2;
      pred[0][0][u][3] = p3; pred[0][0][u][4] = p4;
    } else {
      const int sl = q - 1;   // slots 1,2
      pred[0][sl][u][0] = p0; pred[0][sl][u][1] = p1; pred[0][sl][u][2] = p2;
      pred[0][sl][u][3] = p3; pred[0][sl][u][4] = p4;
      pred[1][sl][u][0] = q0; pred[1][sl][u][1] = q1; pred[1][sl][u][2] = q2;
      pred[1][sl][u][3] = q3; pred[1][sl][u][4] = q4;
    }
    __syncthreads();
    if (q < 2) {
      const double o0 = q ? q0 : p0, o1 = q ? q1 : p1, o2 = q ? q2 : p2;
      const double o3 = q ? q3 : p3, o4 = q ? q4 : p4;
      const double a0 = o0 + pred[q][0][u][0] + pred[q][1][u][0] + pred[q][2][u][0];
      const double a1 = o1 + pred[q][0][u][1] + pred[q][1][u][1] + pred[q][2][u][1];
      const double a2 = o2 + pred[q][0][u][2] + pred[q][1][u][2] + pred[q][2][u][2];
      const double a3 = o3 + pred[q][0][u][3] + pred[q][1][u][3] + pred[q][2][u][3];
      const double ae = o4 + pred[q][0][u][4] + pred[q][1][u][4] + pred[q][2][u][4];
      const double xg0 = q ? x10 : x00;
      const double xg1 = q ? x11 : x01;
      const double gi = a0 + fma(wxE[0], xg0, fma(wxE[1], xg1, wxE[8]));
      const double gf = a1 + fma(wxE[2], xg0, fma(wxE[3], xg1, wxE[9]));
      const double gg = a2 + fma(wxE[4], xg0, fma(wxE[5], xg1, wxE[10]));
      const double go = a3 + fma(wxE[6], xg0, fma(wxE[7], xg1, wxE[11]));
      const double cn = sigmoid_d(gf)*c_state + sigmoid_d(gi)*tanh(gg);
      const double hn = sigmoid_d(go)*tanh(cn);
      c_state = cn;
      if (t > 0) (q ? ep1 : ep0)[(t-1)*256 + u] = ae + be_u;
      hls[par ^ 1][q][u] = hn;
    }
    __syncthreads();
    par ^= 1;
  }
  // ep[99] from h^(100)
  {
    double ae0 = 0.0, ae1 = 0.0;
    const double* h0 = hls[par][0];
    const double* h1 = hls[par][1];
    #pragma unroll 8
    for (int k = k0; k < k0 + 64; ++k) {
      const double wv = (double)WET[k*256 + u];
      ae0 = fma(wv, h0[k], ae0);
      ae1 = fma(wv, h1[k], ae1);
    }
    if (q == 0) {
      pred[1][0][u][0] = ae1;
    } else if (q == 1) {
      pred[0][0][u][0] = ae0;
    } else {
      const int sl = q - 1;
      pred[0][sl][u][0] = ae0;
      pred[1][sl][u][0] = ae1;
    }
    __syncthreads();
    if (q < 2) {
      const double own = q ? ae1 : ae0;
      const double ae = own + pred[q][0][u][0] + pred[q][1][u][0] + pred[q][2][u][0];
      (q ? ep1 : ep0)[99*256 + u] = ae + be_u;
    }
    __syncthreads();   // fence pred reads vs decoder-prologue deposits (R17b)
  }

  // ===================== decoder =====================
  // both batches' masks tracked block-uniformly in every thread
  unsigned long long ma0 = 0ull, ma1 = 0ull;   // b0 mask
  unsigned long long mb0 = 0ull, mb1 = 0ull;   // b1 mask
  float lp_acc = 0.0f;

  // ---- prologue: LSTM(0) with din = start (h,c carry over from encoder) ----
  {
    const double sx0 = (double)start[0];
    const double sx1 = (double)start[1];
    double p0 = 0.0, p1 = 0.0, p2 = 0.0, p3 = 0.0;
    double q0 = 0.0, q1 = 0.0, q2 = 0.0, q3 = 0.0;
    const double* h0 = hls[par][0];
    const double* h1 = hls[par][1];
    #pragma unroll 8
    for (int k = k0; k < k0 + 64; ++k) {
      const double hk0 = h0[k];
      const double hk1 = h1[k];
      const float4 wf = *(const float4*)(WHD + k*1024 + u*4);
      const double wx = (double)wf.x, wy = (double)wf.y;
      const double wz = (double)wf.z, ww = (double)wf.w;
      p0 = fma(wx, hk0, p0);  q0 = fma(wx, hk1, q0);
      p1 = fma(wy, hk0, p1);  q1 = fma(wy, hk1, q1);
      p2 = fma(wz, hk0, p2);  q2 = fma(wz, hk1, q2);
      p3 = fma(ww, hk0, p3);  q3 = fma(ww, hk1, q3);
    }
    if (q == 0) {
      pred[1][0][u][0] = q0; pred[1][0][u][1] = q1;
      pred[1][0][u][2] = q2; pred[1][0][u][3] = q3;
    } else if (q == 1) {
      pred[0][0][u][0] = p0; pred[0][0][u][1] = p1;
      pred[0][0][u][2] = p2; pred[0][0][u][3] = p3;
    } else {
      const int sl = q - 1;
      pred[0][sl][u][0] = p0; pred[0][sl][u][1] = p1;
      pred[0][sl][u][2] = p2; pred[0][sl][u][3] = p3;
      pred[1][sl][u][0] = q0; pred[1][sl][u][1] = q1;
      pred[1][sl][u][2] = q2; pred[1][sl][u][3] = q3;
    }
    __syncthreads();
    if (q < 2) {
      const double o0 = q ? q0 : p0, o1 = q ? q1 : p1;
      const double o2 = q ? q2 : p2, o3 = q ? q3 : p3;
      const double a0 = o0 + pred[q][0][u][0] + pred[q][1][u][0] + pred[q][2][u][0];
      const double a1 = o1 + pred[q][0][u][1] + pred[q][1][u][1] + pred[q][2][u][1];
      const double a2 = o2 + pred[q][0][u][2] + pred[q][1][u][2] + pred[q][2][u][2];
      const double a3 = o3 + pred[q][0][u][3] + pred[q][1][u][3] + pred[q][2][u][3];
      const double gi = a0 + fma(wxD[0], sx0, fma(wxD[1], sx1, wxD[8]));
      const double gf = a1 + fma(wxD[2], sx0, fma(wxD[3], sx1, wxD[9]));
      const double gg = a2 + fma(wxD[4], sx0, fma(wxD[5], sx1, wxD[10]));
      const double go = a3 + fma(wxD[6], sx0, fma(wxD[7], sx1, wxD[11]));
      const double cn = sigmoid_d(gf)*c_state + sigmoid_d(gi)*tanh(gg);
      const double hn = sigmoid_d(go)*tanh(cn);
      c_state = cn;
      hls[par ^ 1][q][u] = hn;
    }
    __syncthreads();
    par ^= 1;
  }

  for (int t = 0; t < 100; ++t) {
    // ---- merged k-loop over h(t): dec_proj(t) + LSTM partials for t+1 ----
    double go0, go1, go2, go3;        // own-batch survivors (regs thru select)
    {
      double p0 = 0.0, p1 = 0.0, p2 = 0.0, p3 = 0.0, pd = 0.0;  // b0
      double q0 = 0.0, q1 = 0.0, q2 = 0.0, q3 = 0.0, qd = 0.0;  // b1
      const double* h0 = hls[par][0];
      const double* h1 = hls[par][1];
      #pragma unroll 8
      for (int k = k0; k < k0 + 64; ++k) {
        const double hk0 = h0[k];
        const double hk1 = h1[k];
        const float4 wf = *(const float4*)(WHD + k*1024 + u*4);
        const float  wd = WDT[k*256 + u];
        const double wx = (double)wf.x, wy = (double)wf.y;
        const double wz = (double)wf.z, ww = (double)wf.w;
        const double wv = (double)wd;
        p0 = fma(wx, hk0, p0);  q0 = fma(wx, hk1, q0);
        p1 = fma(wy, hk0, p1);  q1 = fma(wy, hk1, q1);
        p2 = fma(wz, hk0, p2);  q2 = fma(wz, hk1, q2);
        p3 = fma(ww, hk0, p3);  q3 = fma(ww, hk1, q3);
        pd = fma(wv, hk0, pd);  qd = fma(wv, hk1, qd);
      }
      // LSTM partial deposits (streams 0..3) -- unchanged from R19
      if (q == 0) {
        pred[1][0][u][0] = q0; pred[1][0][u][1] = q1;
        pred[1][0][u][2] = q2; pred[1][0][u][3] = q3;
      } else if (q == 1) {
        pred[0][0][u][0] = p0; pred[0][0][u][1] = p1;
        pred[0][0][u][2] = p2; pred[0][0][u][3] = p3;
      } else {
        const int sl = q - 1;
        pred[0][sl][u][0] = p0; pred[0][sl][u][1] = p1;
        pred[0][sl][u][2] = p2; pred[0][sl][u][3] = p3;
        pred[1][sl][u][0] = q0; pred[1][sl][u][1] = q1;
        pred[1][sl][u][2] = q2; pred[1][sl][u][3] = q3;
      }
      // R21: dp partials from ALL quarters -> pdp (score waves combine)
      pdp[0][q][u] = pd;
      pdp[1][q][u] = qd;
      go0 = q ? q0 : p0;  go1 = q ? q1 : p1;
      go2 = q ? q2 : p2;  go3 = q ? q3 : p3;
    }
    // compact unmasked-s list for own batch (q<2), masks from step start
    if (q < 2 && u < 100) {
      const unsigned long long km0 = q ? mb0 : ma0;
      const unsigned long long km1 = q ? mb1 : ma1;
      const unsigned long long um0 = ~km0;
      const unsigned long long um1 = (~km1) & 0xFFFFFFFFFull;  // 36 bits
      bool unm; int pre;
      if (u < 64) {
        unm = ((um0 >> u) & 1ull) != 0ull;
        pre = __popcll(um0 & ((1ull << u) - 1ull));
      } else {
        const int r = u - 64;
        unm = ((um1 >> r) & 1ull) != 0ull;
        pre = __popcll(um0) + __popcll(um1 & ((1ull << r) - 1ull));
      }
      if (unm) sm[q].slist[pre] = (unsigned char)u;
    }
    __syncthreads();                                   // bar1 (merged)
    // ---- f64-exact scores: waves 0-7 b0, waves 8-15 b1 ----
    // dp combined per-lane from pdp: (((q0+q1)+q2)+q3)+bd -- b0 == R19 order;
    // b1 differs only by commutative q1+q0 -> q0+q1 (bit-identical).
    // Depth-3 rotating prefetch (R19).
    {
      const int scnt = 100 - t;
      const int bw = w >> 3;
      const int wi = w & 7;
      const double* epb = bw ? ep1 : ep0;
      const int i4 = lane * 4;
      const double dpq0 = pdp[bw][0][i4+0] + pdp[bw][1][i4+0]
                        + pdp[bw][2][i4+0] + pdp[bw][3][i4+0] + bdq0;
      const double dpq1 = pdp[bw][0][i4+1] + pdp[bw][1][i4+1]
                        + pdp[bw][2][i4+1] + pdp[bw][3][i4+1] + bdq1;
      const double dpq2 = pdp[bw][0][i4+2] + pdp[bw][1][i4+2]
                        + pdp[bw][2][i4+2] + pdp[bw][3][i4+2] + bdq2;
      const double dpq3 = pdp[bw][0][i4+3] + pdp[bw][1][i4+3]
                        + pdp[bw][2][i4+3] + pdp[bw][3][i4+3] + bdq3;
      int sA = 0, sB = 0, sC = 0;
      double2 A01 = {0.0, 0.0}, A23 = {0.0, 0.0};
      double2 B01 = {0.0, 0.0}, B23 = {0.0, 0.0};
      double2 C01 = {0.0, 0.0}, C23 = {0.0, 0.0};
      if (wi < scnt) {
        sA = (int)sm[bw].slist[wi];
        const double* er = epb + sA*256 + i4;
        A01 = *(const double2*)(er);  A23 = *(const double2*)(er + 2);
      }
      if (wi + 8 < scnt) {
        sB = (int)sm[bw].slist[wi + 8];
        const double* er = epb + sB*256 + i4;
        B01 = *(const double2*)(er);  B23 = *(const double2*)(er + 2);
      }
      if (wi + 16 < scnt) {
        sC = (int)sm[bw].slist[wi + 16];
        const double* er = epb + sC*256 + i4;
        C01 = *(const double2*)(er);  C23 = *(const double2*)(er + 2);
      }
      for (int i = wi; i < scnt; i += 8) {
        // issue the load 3 rounds ahead FIRST, then compute round i
        int sN = 0;
        double2 N01 = {0.0, 0.0}, N23 = {0.0, 0.0};
        const int inx = i + 24;
        if (inx < scnt) {
          sN = (int)sm[bw].slist[inx];
          const double* er = epb + sN*256 + i4;
          N01 = *(const double2*)(er);  N23 = *(const double2*)(er + 2);
        }
        double p =        tanh_att_d(A01.x + dpq0) * vq0;
        p = __builtin_fma(tanh_att_d(A01.y + dpq1), vq1, p);
        p = __builtin_fma(tanh_att_d(A23.x + dpq2), vq2, p);
        p = __builtin_fma(tanh_att_d(A23.y + dpq3), vq3, p);
        p = wave64_sum_d(p);
        if (lane == 0) sm[bw].sredf[sA] = p;
        sA = sB; A01 = B01; A23 = B23;
        sB = sC; B01 = C01; B23 = C23;
        sC = sN; C01 = N01; C23 = N23;
      }
    }
    __syncthreads();                                   // bar2
    // ---- np-faithful fp32 selection, condensed into wave 0 / wave 8 ----
    if ((w & 7) == 0) {
      const int bb = w >> 3;
      const unsigned long long km0 = bb ? mb0 : ma0;
      const unsigned long long km1 = bb ? mb1 : ma1;
      const bool mk0 = ((km0 >> lane) & 1ull) != 0ull;
      const bool mk1 = (lane < 36) ? (((km1 >> lane) & 1ull) != 0ull) : true;
      const int  s1i = 64 + (lane < 36 ? lane : 0);
      // single rounding of the exact score to fp32 (reference dtype)
      const float sc0 = mk0 ? -__builtin_inff()
                            : (float)(sm[bb].sredf[lane] + vb0);
      const float sc1 = mk1 ? -__builtin_inff()
                            : (float)(sm[bb].sredf[s1i] + vb0);
      // m = max(scores), fp32 -- identical fmax tree as frozen block
      float mv = fmaxf(sc0, sc1);
      #pragma unroll
      for (int mm = 1; mm < 64; mm <<= 1)
        mv = fmaxf(mv, __shfl_xor(mv, mm, 64));
      // evals = expf(s - m), staged to LDS in the frozen index layout
      sm[bb].evals[lane] = expf(__fsub_rn(sc0, mv));
      if (lane < 36) sm[bb].evals[64 + lane] = expf(__fsub_rn(sc1, mv));
      // same-wave LDS visibility: fence compiler + lgkm before read-back
      asm volatile("s_waitcnt lgkmcnt(0)" ::: "memory");
      __builtin_amdgcn_sched_barrier(0);
      // numpy pairwise_sum for n=100 (frozen): 8 accumulators over 0..95,
      // combine ((r0+r1)+(r2+r3))+((r4+r5)+(r6+r7)), sequential tail 96..99
      float rr[8];
      #pragma unroll
      for (int j = 0; j < 8; ++j) rr[j] = sm[bb].evals[j];
      for (int i = 8; i < 96; i += 8) {
        #pragma unroll
        for (int j = 0; j < 8; ++j) rr[j] = __fadd_rn(rr[j], sm[bb].evals[i + j]);
      }
      float res = __fadd_rn(
          __fadd_rn(__fadd_rn(rr[0], rr[1]), __fadd_rn(rr[2], rr[3])),
          __fadd_rn(__fadd_rn(rr[4], rr[5]), __fadd_rn(rr[6], rr[7])));
      res = __fadd_rn(res, sm[bb].evals[96]);
      res = __fadd_rn(res, sm[bb].evals[97]);
      res = __fadd_rn(res, sm[bb].evals[98]);
      res = __fadd_rn(res, sm[bb].evals[99]);
      const float L = logf(res);
      // lp = fl(fl(s - m) - L); argmax(lp), first index on ties (frozen)
      const float lp0 = __fsub_rn(__fsub_rn(sc0, mv), L);
      const float lp1 = (lane < 36)
          ? __fsub_rn(__fsub_rn(sc1, mv), L)
          : -__builtin_inff();
      float bv; int bi;
      if (lp0 >= lp1) { bv = lp0; bi = lane; } else { bv = lp1; bi = 64 + lane; }
      #pragma unroll
      for (int mm = 1; mm < 64; mm <<= 1) {
        const float ov = __shfl_xor(bv, mm, 64);
        const int   oi = __shfl_xor(bi, mm, 64);
        if (ov > bv || (ov == bv && oi < bi)) { bv = ov; bi = oi; }
      }
      if (lane == 0) { sm[bb].bc_sel = bi; sm[bb].bc_lp = bv; }
    }
    __syncthreads();                                   // bar3
    const int sel0 = __builtin_amdgcn_readfirstlane(sm[0].bc_sel);
    const int sel1 = __builtin_amdgcn_readfirstlane(sm[1].bc_sel);
    lp_acc = __fadd_rn(lp_acc, sm[q & 1].bc_lp);  // np axis-0 sum: seq fp32
    if (sel0 < 64) ma0 |= (1ull << sel0); else ma1 |= (1ull << (sel0 - 64));
    if (sel1 < 64) mb0 |= (1ull << sel1); else mb1 |= (1ull << (sel1 - 64));
    if (tid == 0)   out[b0*100 + t] = (float)sel0;
    if (tid == 256) out[b1*100 + t] = (float)sel1;
    // ---- finalize LSTM(t+1): gates = partials + Wih*din + bias ----
    if (t < 99) {
      if (q < 2) {
        const int sel = q ? sel1 : sel0;
        const int bb  = q ? b1 : b0;
        const double xd0 = (double)x[(bb*100 + sel)*2 + 0];  // uniform load
        const double xd1 = (double)x[(bb*100 + sel)*2 + 1];
        const double a0 = go0 + pred[q][0][u][0] + pred[q][1][u][0] + pred[q][2][u][0];
        const double a1 = go1 + pred[q][0][u][1] + pred[q][1][u][1] + pred[q][2][u][1];
        const double a2 = go2 + pred[q][0][u][2] + pred[q][1][u][2] + pred[q][2][u][2];
        const double a3 = go3 + pred[q][0][u][3] + pred[q][1][u][3] + pred[q][2][u][3];
        const double gi = a0 + fma(wxD[0], xd0, fma(wxD[1], xd1, wxD[8]));
        const double gf = a1 + fma(wxD[2], xd0, fma(wxD[3], xd1, wxD[9]));
        const double gg = a2 + fma(wxD[4], xd0, fma(wxD[5], xd1, wxD[10]));
        const double go = a3 + fma(wxD[6], xd0, fma(wxD[7], xd1, wxD[11]));
        const double cn = sigmoid_d(gf)*c_state + sigmoid_d(gi)*tanh(gg);
        const double hn = sigmoid_d(go)*tanh(cn);
        c_state = cn;
        hls[par ^ 1][q][u] = hn;
      }
      par ^= 1;
    }
    __syncthreads();                                   // bar4
  }

  // ---------------- outputs ----------------
  if (tid == 0)   out[51200 + b0] = lp_acc;
  if (tid == 256) out[51200 + b1] = lp_acc;
  if (q < 2) out[51712 + (q ? b1 : b0)*256 + u] = (float)hls[par][q][u];
}

extern "C" void kernel_launch(void* const* d_in, const int* in_sizes, int n_in,
                              void* d_out, int out_size, void* d_ws, size_t ws_size,
                              hipStream_t stream) {
  const float* x     = (const float*)d_in[0];
  const float* eWih  = (const float*)d_in[1];
  const float* eWhh  = (const float*)d_in[2];
  const float* ebih  = (const float*)d_in[3];
  const float* ebhh  = (const float*)d_in[4];
  const float* dWih  = (const float*)d_in[5];
  const float* dWhh  = (const float*)d_in[6];
  const float* dbih  = (const float*)d_in[7];
  const float* dbhh  = (const float*)d_in[8];
  const float* We    = (const float*)d_in[9];
  const float* be    = (const float*)d_in[10];
  const float* Wd    = (const float*)d_in[11];
  const float* bd    = (const float*)d_in[12];
  const float* vw    = (const float*)d_in[13];
  const float* vb    = (const float*)d_in[14];
  const float* start = (const float*)d_in[15];
  char* ws    = (char*)d_ws;
  float* outp = (float*)d_out;

  ptrnet_prep<<<dim3(512), dim3(256), 0, stream>>>(
      eWih, eWhh, ebih, ebhh, dWih, dWhh, dbih, dbhh, We, Wd, ws);

  ptrnet_main<<<dim3(256), dim3(1024), 0, stream>>>(ws, x, be, bd, vw, vb,
                                                    start, outp);
}